// Round 9
// baseline (4801.928 us; speedup 1.0000x reference)
//
#include <hip/hip_runtime.h>
#include <stdint.h>

#define N_PTS   65536
#define N_GRP   1024
#define K_NB    32
#define F_DIM   64

// ---- FPS (single block, compacted chunk-pruned, u32 ds_max chunk maxima) ----
#define FPS1_THR 1024
#define NCHUNK   1024
#define CPTS     64
#define NBINS    4096        // 16x16x16 morton grid

// ---- fallback FPS (R1-proven agent-scope), only if ws too small ----
#define F2_BLOCKS 16
#define F2_THR    512
#define F2_TT     (F2_BLOCKS*F2_THR)
#define F2_P      (N_PTS / F2_TT)

// ---------- helpers ----------
__device__ __forceinline__ unsigned long long packMinKey(float v, unsigned int idx) {
  unsigned int b = __float_as_uint(v);
  b = (b & 0x80000000u) ? ~b : (b | 0x80000000u);
  return ((unsigned long long)b << 32) | idx;
}
__device__ __forceinline__ float unpackMinVal(unsigned long long k) {
  unsigned int b = (unsigned int)(k >> 32);
  b = (b & 0x80000000u) ? (b & 0x7FFFFFFFu) : ~b;
  return __uint_as_float(b);
}
__device__ __forceinline__ unsigned spread4(unsigned b) {
  return (b & 1u) | ((b & 2u) << 2) | ((b & 4u) << 4) | ((b & 8u) << 6);
}
__device__ __forceinline__ unsigned morton_bid(float a, float b, float c) {
  const float S = 16.0f / 11.0f;
  int bx = (int)((a + 5.5f) * S);
  int by = (int)((b + 5.5f) * S);
  int bz = (int)((c + 5.5f) * S);
  bx = min(max(bx, 0), 15); by = min(max(by, 0), 15); bz = min(max(bz, 0), 15);
  return spread4((unsigned)bx) | (spread4((unsigned)by) << 1) | (spread4((unsigned)bz) << 2);
}

// ---------- Phase 1: FPS — one block; ds_max_u32 chunk maxima, two-step winner ----------
__global__ void __launch_bounds__(FPS1_THR)
fps_kernel(const float* __restrict__ x, float4* __restrict__ xs4,
           float* __restrict__ dd, float* __restrict__ centers)
{
  __shared__ __align__(16) char smem[32768];
  unsigned* sA    = (unsigned*)smem;                  // scan ping   [0,16K)   (transient)
  unsigned* sB    = (unsigned*)(smem + 16384);        // scan pong   [16K,32K) (transient)
  unsigned* ckeys = (unsigned*)smem;                  // [0,4K)  chunk max dist-bits (u32)
  unsigned* act   = (unsigned*)(smem + 4096);         // [4K,8K)  active chunk list
  unsigned* act2  = (unsigned*)(smem + 8192);         // [8K,12K) winner-candidate list
  float* bxl = (float*)(smem + 4096);                 // bbox arrays [4K,28K) (pre-loop only)
  float* bxh = bxl + 1024;
  float* byl = bxl + 2048;
  float* byh = bxl + 3072;
  float* bzl = bxl + 4096;
  float* bzh = bxl + 5120;
  __shared__ unsigned red[16];
  __shared__ float bc[3];
  __shared__ int s_nact, s_ncand;

  const int tid = threadIdx.x, lane = tid & 63, wid = tid >> 6;

  // ---- histogram
#pragma unroll
  for (int j = 0; j < NBINS/FPS1_THR; ++j) sA[tid + j*FPS1_THR] = 0u;
  __syncthreads();
  for (int i = tid; i < N_PTS; i += FPS1_THR) {
    float a = x[i*3+0], b = x[i*3+1], c = x[i*3+2];
    atomicAdd(&sA[morton_bid(a,b,c)], 1u);
  }
  __syncthreads();

  // ---- inclusive scan (ping-pong, 12 passes -> result in sA), exclusive cursors in sB
  {
    unsigned* src = sA; unsigned* dst = sB;
    for (int off = 1; off < NBINS; off <<= 1) {
#pragma unroll
      for (int j = 0; j < NBINS/FPS1_THR; ++j) {
        int i = tid + j*FPS1_THR;
        unsigned v = src[i];
        if (i >= off) v += src[i-off];
        dst[i] = v;
      }
      __syncthreads();
      unsigned* t_ = src; src = dst; dst = t_;
    }
#pragma unroll
    for (int j = 0; j < NBINS/FPS1_THR; ++j) {
      int i = tid + j*FPS1_THR;
      sB[i] = (i == 0) ? 0u : sA[i-1];
    }
    __syncthreads();
  }

  // ---- scatter (chunk-major [c][k]); init d
  for (int i = tid; i < N_PTS; i += FPS1_THR) {
    float a = x[i*3+0], b = x[i*3+1], c = x[i*3+2];
    unsigned pos = atomicAdd(&sB[morton_bid(a,b,c)], 1u);
    xs4[pos] = make_float4(a, b, c, __uint_as_float((unsigned)i));
    dd[pos]  = 1e10f;
  }
  __syncthreads();

  // ---- per-chunk bbox (wave w -> chunks 64w..64w+63, coalesced)
  for (int cc = 0; cc < 64; ++cc) {
    const int c = wid*64 + cc;
    float4 f = xs4[c*CPTS + lane];
    float xl = f.x, xh = f.x, yl = f.y, yh = f.y, zl = f.z, zh = f.z;
#pragma unroll
    for (int off = 32; off; off >>= 1) {
      xl = fminf(xl, __shfl_xor(xl, off)); xh = fmaxf(xh, __shfl_xor(xh, off));
      yl = fminf(yl, __shfl_xor(yl, off)); yh = fmaxf(yh, __shfl_xor(yh, off));
      zl = fminf(zl, __shfl_xor(zl, off)); zh = fmaxf(zh, __shfl_xor(zh, off));
    }
    if (lane == 0) { bxl[c]=xl; bxh[c]=xh; byl[c]=yl; byh[c]=yh; bzl[c]=zl; bzh[c]=zh; }
  }
  __syncthreads();
  const float rxl = bxl[tid], rxh = bxh[tid];
  const float ryl = byl[tid], ryh = byh[tid];
  const float rzl = bzl[tid], rzh = bzh[tid];
  __syncthreads();                          // bbox area free -> act/act2

  ckeys[tid] = __float_as_uint(1e10f);      // forces all chunks active in round 1
  if (tid == 0) { s_nact = 0; s_ncand = 0; }
  __syncthreads();

  float cx = x[0], cy = x[1], cz = x[2];
  if (tid == 0) { centers[0] = cx; centers[1] = cy; centers[2] = cz; }

  for (int r = 1; r < N_GRP; ++r) {
    // ---- A: bbox prune, reset own ckey if active, ballot-compact
    const float cdmax = __uint_as_float(ckeys[tid]);
    float dxl = fmaxf(fmaxf(rxl - cx, cx - rxh), 0.0f);
    float dyl = fmaxf(fmaxf(ryl - cy, cy - ryh), 0.0f);
    float dzl = fmaxf(fmaxf(rzl - cz, cz - rzh), 0.0f);
    float b2 = fmaf(dzl, dzl, fmaf(dyl, dyl, dxl*dxl));
    const bool active = b2 < cdmax * 1.0001f;   // exact-safe margin
    if (active) ckeys[tid] = 0u;                // own entry only; re-filled in B
    const unsigned long long bal = __ballot(active);
    int base = 0;
    if (lane == 0) { int cnt = __popcll(bal); if (cnt) base = atomicAdd(&s_nact, cnt); }
    base = __shfl(base, 0);
    if (active) { int rank = __popcll(bal & ((1ull << lane) - 1ull)); act[base + rank] = (unsigned)tid; }
    __syncthreads();                        // B1

    // ---- B: one chunk per wave round-robin; no shuffle chains, ds_max_u32 per lane
    const int n = s_nact;
    for (int j = wid; j < n; j += 16) {
      const int c = (int)act[j];
      const int sidx = c*CPTS + lane;
      float4 f = xs4[sidx];
      float dk = dd[sidx];
      float e0 = f.x - cx, e1 = f.y - cy, e2 = f.z - cz;
      float dist = fmaf(e2,e2, fmaf(e1,e1, e0*e0));   // byte-identical chain
      float dn = fminf(dk, dist);
      dd[sidx] = dn;
      atomicMax(&ckeys[c], __float_as_uint(dn));      // ds_max_u32 (dn>=0: bit order==value order)
    }
    __syncthreads();                        // B2

    // ---- block u32 max over 1024 chunk maxima
    unsigned k = ckeys[tid];
#pragma unroll
    for (int off = 32; off; off >>= 1) {
      unsigned o = (unsigned)__shfl_xor((int)k, off);
      k = k > o ? k : o;
    }
    if (lane == 0) red[wid] = k;
    if (tid == 0) s_nact = 0;
    __syncthreads();                        // B3
    unsigned m = red[lane & 15];
#pragma unroll
    for (int off = 1; off < 16; off <<= 1) {
      unsigned o = (unsigned)__shfl_xor((int)m, off);
      m = m > o ? m : o;
    }

    // ---- candidate chunks (ckeys == m), usually 1
    const bool cand = (ckeys[tid] == m);
    const unsigned long long bal2 = __ballot(cand);
    int base2 = 0;
    if (lane == 0) { int cnt = __popcll(bal2); if (cnt) base2 = atomicAdd(&s_ncand, cnt); }
    base2 = __shfl(base2, 0);
    if (cand) { int rank = __popcll(bal2 & ((1ull << lane) - 1ull)); act2[base2 + rank] = (unsigned)tid; }
    __syncthreads();                        // B4

    // ---- winner: wave 0 rescans candidates, min original index among dd==m
    if (wid == 0) {
      const int nc = s_ncand;
      unsigned best = 0xFFFFFFFFu;
      for (int j = 0; j < nc; ++j) {
        const int c = (int)act2[j];
        const int sidx = c*CPTS + lane;
        unsigned db = __float_as_uint(dd[sidx]);
        unsigned oi = __float_as_uint(xs4[sidx].w);
        unsigned v = (db == m) ? oi : 0xFFFFFFFFu;
        best = best < v ? best : v;
      }
#pragma unroll
      for (int off = 32; off; off >>= 1) {
        unsigned o = (unsigned)__shfl_xor((int)best, off);
        best = best < o ? best : o;
      }
      if (lane == 0) {
        float wx = x[best*3+0], wy = x[best*3+1], wz = x[best*3+2];
        bc[0] = wx; bc[1] = wy; bc[2] = wz;
        centers[r*3+0] = wx; centers[r*3+1] = wy; centers[r*3+2] = wz;
        s_ncand = 0;
      }
    }
    __syncthreads();                        // B5
    cx = bc[0]; cy = bc[1]; cz = bc[2];
  }
}

// ---------- fallback FPS (only if ws too small) ----------
__global__ void __launch_bounds__(F2_THR)
fps_safe_kernel(const float* __restrict__ x, unsigned long long* __restrict__ slots,
                unsigned int* __restrict__ cnts, float* __restrict__ centers)
{
  __shared__ unsigned long long red[F2_THR/64];
  const int t = blockIdx.x * F2_THR + threadIdx.x;
  float px[F2_P], py[F2_P], pz[F2_P], d[F2_P];
#pragma unroll
  for (int k = 0; k < F2_P; ++k) {
    int p = t + k * F2_TT;
    px[k] = x[p*3+0]; py[k] = x[p*3+1]; pz[k] = x[p*3+2];
    d[k] = 1e10f;
  }
  float cx = x[0], cy = x[1], cz = x[2];
  if (blockIdx.x == 0 && threadIdx.x == 0) {
    centers[0] = cx; centers[1] = cy; centers[2] = cz;
  }
  for (int r = 1; r < N_GRP; ++r) {
    unsigned long long best = 0ull;
#pragma unroll
    for (int k = 0; k < F2_P; ++k) {
      float e0 = px[k]-cx, e1 = py[k]-cy, e2 = pz[k]-cz;
      float dist = fmaf(e2,e2, fmaf(e1,e1, e0*e0));
      float dn = fminf(d[k], dist);
      d[k] = dn;
      unsigned long long pk = ((unsigned long long)__float_as_uint(dn) << 32)
                            | (0xFFFFFFFFu - (unsigned)(t + k*F2_TT));
      if (pk > best) best = pk;
    }
#pragma unroll
    for (int off = 32; off; off >>= 1) {
      unsigned long long o = __shfl_down(best, off);
      if (o > best) best = o;
    }
    const int wid = threadIdx.x >> 6;
    if ((threadIdx.x & 63) == 0) red[wid] = best;
    __syncthreads();
    if (threadIdx.x == 0) {
#pragma unroll
      for (int w = 1; w < F2_THR/64; ++w) if (red[w] > best) best = red[w];
      atomicMax(&slots[r], best);
      __hip_atomic_fetch_add(&cnts[r], 1u, __ATOMIC_RELEASE, __HIP_MEMORY_SCOPE_AGENT);
      while (__hip_atomic_load(&cnts[r], __ATOMIC_ACQUIRE, __HIP_MEMORY_SCOPE_AGENT) < F2_BLOCKS)
        __builtin_amdgcn_s_sleep(1);
      red[0] = __hip_atomic_load(&slots[r], __ATOMIC_RELAXED, __HIP_MEMORY_SCOPE_AGENT);
    }
    __syncthreads();
    const unsigned long long win = red[0];
    const int widx = (int)(0xFFFFFFFFu - (unsigned int)(win & 0xFFFFFFFFull));
    cx = x[widx*3+0]; cy = x[widx*3+1]; cz = x[widx*3+2];
    if (blockIdx.x == 0 && threadIdx.x == 0) {
      centers[r*3+0] = cx; centers[r*3+1] = cy; centers[r*3+2] = cz;
    }
    __syncthreads();
  }
}

// ---------- Phase 2: per-group exact 32 smallest (proven) ----------
#define TKT 256
#define CAP 3072

__global__ void __launch_bounds__(TKT)
topk_kernel(const float* __restrict__ x, const float* __restrict__ feat,
            const float* __restrict__ centers, float* __restrict__ out)
{
  __shared__ float cv[CAP];
  __shared__ int   ci[CAP];
  __shared__ int   s_cnt;
  __shared__ float s_thr;
  __shared__ float selv[K_NB];
  __shared__ int   seli[K_NB];

  const int g = blockIdx.x, tid = threadIdx.x;
  const float cx = centers[g*3+0], cy = centers[g*3+1], cz = centers[g*3+2];
  const float c2 = fmaf(cz,cz, fmaf(cy,cy, cx*cx));
  if (tid == 0) { s_cnt = 0; s_thr = __builtin_inff(); }
  __syncthreads();

  const int CH = N_PTS / (TKT*8);
  for (int chunk = 0; chunk < CH; ++chunk) {
    const float lthr = s_thr;
#pragma unroll
    for (int k = 0; k < 8; ++k) {
      int p = (chunk*8 + k)*TKT + tid;
      float q0 = x[p*3+0], q1 = x[p*3+1], q2 = x[p*3+2];
      float dot  = fmaf(cz,q2, fmaf(cy,q1, cx*q0));
      float pp   = fmaf(q2,q2, fmaf(q1,q1, q0*q0));
      float dist = fmaf(-2.0f, dot, c2) + pp;
      if (dist <= lthr) {
        int pos = atomicAdd(&s_cnt, 1);
        cv[pos] = dist; ci[pos] = p;
      }
    }
    __syncthreads();
    const int n = s_cnt;
    const bool last = (chunk == CH-1);
    if (n > (CAP - TKT*8) || last) {
      if (tid < 64) {
        for (int it = 0; it < K_NB; ++it) {
          unsigned long long lk = ~0ull;
          for (int j = tid; j < n; j += 64) {
            unsigned long long kk = packMinKey(cv[j], (unsigned)ci[j]);
            if (kk < lk) lk = kk;
          }
#pragma unroll
          for (int off = 32; off; off >>= 1) {
            unsigned long long o = __shfl_xor(lk, off);
            if (o < lk) lk = o;
          }
          const int mi = (int)(unsigned int)(lk & 0xFFFFFFFFull);
          for (int j = tid; j < n; j += 64)
            if (ci[j] == mi) cv[j] = __builtin_inff();
          if (tid == 0) { selv[it] = unpackMinVal(lk); seli[it] = mi; }
        }
      }
      __syncthreads();
      if (!last) {
        if (tid < K_NB) { cv[tid] = selv[tid]; ci[tid] = seli[tid]; }
        if (tid == 0)   { s_cnt = K_NB; s_thr = selv[K_NB-1]; }
        __syncthreads();
      }
    }
  }

  const long base = (long)g * (K_NB*F_DIM);
#pragma unroll
  for (int m = 0; m < (K_NB*F_DIM)/TKT; ++m) {
    int lin = m*TKT + tid;
    int j = lin >> 6, c = lin & 63;
    out[base + lin] = feat[(long)seli[j]*F_DIM + c];
  }
}

// ---------- Phase 3: per-point argmin over 1024 centers (proven) ----------
__global__ void __launch_bounds__(256)
argmin_kernel(const float* __restrict__ x, const float* __restrict__ centers,
              float* __restrict__ outIdx)
{
  __shared__ float scx[N_GRP], scy[N_GRP], scz[N_GRP], sc2[N_GRP];
  for (int i = threadIdx.x; i < N_GRP; i += 256) {
    float a = centers[i*3+0], b = centers[i*3+1], c = centers[i*3+2];
    scx[i]=a; scy[i]=b; scz[i]=c;
    sc2[i] = fmaf(c,c, fmaf(b,b, a*a));
  }
  __syncthreads();
  const int p = blockIdx.x*256 + threadIdx.x;
  const float q0 = x[p*3+0], q1 = x[p*3+1], q2 = x[p*3+2];
  const float pp = fmaf(q2,q2, fmaf(q1,q1, q0*q0));
  float best = __builtin_inff(); int bi = 0;
#pragma unroll 4
  for (int c = 0; c < N_GRP; ++c) {
    float dot  = fmaf(scz[c],q2, fmaf(scy[c],q1, scx[c]*q0));
    float dist = fmaf(-2.0f, dot, sc2[c]) + pp;
    if (dist < best) { best = dist; bi = c; }
  }
  outIdx[p] = (float)bi;
}

// ---------- launch ----------
extern "C" void kernel_launch(void* const* d_in, const int* in_sizes, int n_in,
                              void* d_out, int out_size, void* d_ws, size_t ws_size,
                              hipStream_t stream)
{
  const float* x    = (const float*)d_in[0];
  const float* feat = (const float*)d_in[1];
  float* out = (float*)d_out;
  char* ws = (char*)d_ws;

  float* ctr = (float*)ws;                                   // 12 KiB centers @ 0
  const size_t DD_OFF  = 65536;                              // 256 KiB d array
  const size_t XS_OFF  = DD_OFF + (size_t)N_PTS*4;           // 1 MiB float4 pts
  const size_t NEED    = XS_OFF + (size_t)N_PTS*16;

  if (ws_size >= NEED) {
    float*  dd  = (float*)(ws + DD_OFF);
    float4* xs4 = (float4*)(ws + XS_OFF);
    hipLaunchKernelGGL(fps_kernel, dim3(1), dim3(FPS1_THR), 0, stream, x, xs4, dd, ctr);
  } else {
    unsigned long long* slots = (unsigned long long*)(ws + 16384);
    unsigned int*       cnts  = (unsigned int*)(ws + 24576);
    hipMemsetAsync(ws + 16384, 0, 12288, stream);
    hipLaunchKernelGGL(fps_safe_kernel, dim3(F2_BLOCKS), dim3(F2_THR), 0, stream,
                       x, slots, cnts, ctr);
  }
  hipLaunchKernelGGL(topk_kernel, dim3(N_GRP), dim3(TKT), 0, stream, x, feat, ctr, out);
  hipLaunchKernelGGL(argmin_kernel, dim3(N_PTS/256), dim3(256), 0, stream,
                     x, ctr, out + (size_t)N_GRP*K_NB*F_DIM);
}

// Round 10
// 2985.720 us; speedup vs baseline: 1.6083x; 1.6083x over previous
//
#include <hip/hip_runtime.h>
#include <stdint.h>

#define N_PTS   65536
#define N_GRP   1024
#define K_NB    32
#define F_DIM   64

// ---- FPS (single block, compacted chunk-pruned, 16-lane sub-wave chunks) ----
#define FPS1_THR 1024
#define NCHUNK   1024
#define CPTS     64
#define NBINS    4096        // 16x16x16 morton grid

// ---- fallback FPS (R1-proven agent-scope), only if ws too small ----
#define F2_BLOCKS 16
#define F2_THR    512
#define F2_TT     (F2_BLOCKS*F2_THR)
#define F2_P      (N_PTS / F2_TT)

// ---------- helpers ----------
__device__ __forceinline__ unsigned long long packMinKey(float v, unsigned int idx) {
  unsigned int b = __float_as_uint(v);
  b = (b & 0x80000000u) ? ~b : (b | 0x80000000u);
  return ((unsigned long long)b << 32) | idx;
}
__device__ __forceinline__ float unpackMinVal(unsigned long long k) {
  unsigned int b = (unsigned int)(k >> 32);
  b = (b & 0x80000000u) ? (b & 0x7FFFFFFFu) : ~b;
  return __uint_as_float(b);
}
__device__ __forceinline__ unsigned spread4(unsigned b) {
  return (b & 1u) | ((b & 2u) << 2) | ((b & 4u) << 4) | ((b & 8u) << 6);
}
__device__ __forceinline__ unsigned morton_bid(float a, float b, float c) {
  const float S = 16.0f / 11.0f;
  int bx = (int)((a + 5.5f) * S);
  int by = (int)((b + 5.5f) * S);
  int bz = (int)((c + 5.5f) * S);
  bx = min(max(bx, 0), 15); by = min(max(by, 0), 15); bz = min(max(bz, 0), 15);
  return spread4((unsigned)bx) | (spread4((unsigned)by) << 1) | (spread4((unsigned)bz) << 2);
}

// ---------- Phase 1: FPS — one block; 4 chunks/wave-iter, u64 keys, 3 barriers ----------
__global__ void __launch_bounds__(FPS1_THR)
fps_kernel(const float* __restrict__ x, float4* __restrict__ xs4,
           float* __restrict__ dd, float* __restrict__ centers)
{
  __shared__ __align__(16) char smem[40960];
  unsigned* sA = (unsigned*)smem;                       // scan ping [0,16K)   transient
  unsigned* sB = (unsigned*)(smem + 16384);             // scan pong [16K,32K) transient
  unsigned long long* ckeys = (unsigned long long*)smem;// [0,8K) chunk max u64 keys
  unsigned* act = (unsigned*)(smem + 8192);             // [8K,12K) active chunk list
  float* bxl = (float*)(smem + 12288);                  // bbox [12K,36K) pre-loop only
  float* bxh = bxl + 1024;
  float* byl = bxl + 2048;
  float* byh = bxl + 3072;
  float* bzl = bxl + 4096;
  float* bzh = bxl + 5120;
  __shared__ unsigned long long red[16];
  __shared__ int s_nact;

  const int tid = threadIdx.x, lane = tid & 63, wid = tid >> 6;

  // ---- histogram
#pragma unroll
  for (int j = 0; j < NBINS/FPS1_THR; ++j) sA[tid + j*FPS1_THR] = 0u;
  __syncthreads();
  for (int i = tid; i < N_PTS; i += FPS1_THR) {
    float a = x[i*3+0], b = x[i*3+1], c = x[i*3+2];
    atomicAdd(&sA[morton_bid(a,b,c)], 1u);
  }
  __syncthreads();

  // ---- inclusive scan (ping-pong, 12 passes -> result in sA), exclusive cursors in sB
  {
    unsigned* src = sA; unsigned* dst = sB;
    for (int off = 1; off < NBINS; off <<= 1) {
#pragma unroll
      for (int j = 0; j < NBINS/FPS1_THR; ++j) {
        int i = tid + j*FPS1_THR;
        unsigned v = src[i];
        if (i >= off) v += src[i-off];
        dst[i] = v;
      }
      __syncthreads();
      unsigned* t_ = src; src = dst; dst = t_;
    }
#pragma unroll
    for (int j = 0; j < NBINS/FPS1_THR; ++j) {
      int i = tid + j*FPS1_THR;
      sB[i] = (i == 0) ? 0u : sA[i-1];
    }
    __syncthreads();
  }

  // ---- scatter (chunk-major [c][k]); init d
  for (int i = tid; i < N_PTS; i += FPS1_THR) {
    float a = x[i*3+0], b = x[i*3+1], c = x[i*3+2];
    unsigned pos = atomicAdd(&sB[morton_bid(a,b,c)], 1u);
    xs4[pos] = make_float4(a, b, c, __uint_as_float((unsigned)i));
    dd[pos]  = 1e10f;
  }
  __syncthreads();

  // ---- per-chunk bbox (wave w -> chunks 64w..64w+63, coalesced)
  for (int cc = 0; cc < 64; ++cc) {
    const int c = wid*64 + cc;
    float4 f = xs4[c*CPTS + lane];
    float xl = f.x, xh = f.x, yl = f.y, yh = f.y, zl = f.z, zh = f.z;
#pragma unroll
    for (int off = 32; off; off >>= 1) {
      xl = fminf(xl, __shfl_xor(xl, off)); xh = fmaxf(xh, __shfl_xor(xh, off));
      yl = fminf(yl, __shfl_xor(yl, off)); yh = fmaxf(yh, __shfl_xor(yh, off));
      zl = fminf(zl, __shfl_xor(zl, off)); zh = fmaxf(zh, __shfl_xor(zh, off));
    }
    if (lane == 0) { bxl[c]=xl; bxh[c]=xh; byl[c]=yl; byh[c]=yh; bzl[c]=zl; bzh[c]=zh; }
  }
  __syncthreads();
  const float rxl = bxl[tid], rxh = bxh[tid];
  const float ryl = byl[tid], ryh = byh[tid];
  const float rzl = bzl[tid], rzh = bzh[tid];
  __syncthreads();                          // bbox LDS free -> act reuse

  if (tid == 0) s_nact = 0;
  __syncthreads();

  float cx = x[0], cy = x[1], cz = x[2];
  if (tid == 0) { centers[0] = cx; centers[1] = cy; centers[2] = cz; }
  float cdmax = 1e10f;                      // my chunk's current max-d (register; exact)

  for (int r = 1; r < N_GRP; ++r) {
    // ---- A: bbox prune vs register cdmax, ballot-compact active chunks
    float dxl = fmaxf(fmaxf(rxl - cx, cx - rxh), 0.0f);
    float dyl = fmaxf(fmaxf(ryl - cy, cy - ryh), 0.0f);
    float dzl = fmaxf(fmaxf(rzl - cz, cz - rzh), 0.0f);
    float b2 = fmaf(dzl, dzl, fmaf(dyl, dyl, dxl*dxl));
    const bool active = b2 < cdmax * 1.0001f;   // exact-safe margin
    const unsigned long long bal = __ballot(active);
    int base = 0;
    if (lane == 0) { int cnt = __popcll(bal); if (cnt) base = atomicAdd(&s_nact, cnt); }
    base = __shfl(base, 0);
    if (active) { int rank = __popcll(bal & ((1ull << lane) - 1ull)); act[base + rank] = (unsigned)tid; }
    __syncthreads();                        // B1: act ready

    // ---- B: 4 chunks per wave-iter; 16 lanes x 4 pts each; one 4-step reduce
    const int n = s_nact;
    const int sub = lane >> 4, li = lane & 15;
    for (int bj = wid*4; bj < n; bj += 64) {
      const int jdx = bj + sub;
      const int c = (jdx < n) ? (int)act[jdx] : -1;
      unsigned long long key = 0ull;
      if (c >= 0) {
        const int cb = c*CPTS;
#pragma unroll
        for (int t = 0; t < 4; ++t) {
          const int sidx = cb + li + 16*t;
          float4 f = xs4[sidx];
          float dk = dd[sidx];
          float e0 = f.x - cx, e1 = f.y - cy, e2 = f.z - cz;
          float dist = fmaf(e2,e2, fmaf(e1,e1, e0*e0));   // byte-identical chain
          float dn = fminf(dk, dist);
          dd[sidx] = dn;
          unsigned long long kk = ((unsigned long long)__float_as_uint(dn) << 32)
                                | (unsigned long long)(0xFFFFFFFFu - __float_as_uint(f.w));
          if (kk > key) key = kk;
        }
      }
#pragma unroll
      for (int off = 1; off < 16; off <<= 1) {            // reduce within 16-lane group
        unsigned long long o = __shfl_xor(key, off);
        if (o > key) key = o;
      }
      if (c >= 0 && li == 0) ckeys[c] = key;
    }
    __syncthreads();                        // B2: ckeys consistent

    // ---- block argmax over 1024 u64 chunk keys; refresh own cdmax from same read
    unsigned long long kown = ckeys[tid];
    cdmax = __uint_as_float((unsigned)(kown >> 32));
    unsigned long long k = kown;
#pragma unroll
    for (int off = 32; off; off >>= 1) {
      unsigned long long o = __shfl_xor(k, off);
      if (o > k) k = o;
    }
    if (lane == 0) red[wid] = k;
    if (tid == 0) s_nact = 0;
    __syncthreads();                        // B3: red ready
    unsigned long long k2 = red[lane & 15];
#pragma unroll
    for (int off = 1; off < 16; off <<= 1) {
      unsigned long long o = __shfl_xor(k2, off);
      if (o > k2) k2 = o;
    }
    const unsigned orig = 0xFFFFFFFFu - (unsigned)(k2 & 0xFFFFFFFFull);
    cx = x[orig*3+0]; cy = x[orig*3+1]; cz = x[orig*3+2];  // same-address broadcast load
    if (tid == 0) { centers[r*3+0]=cx; centers[r*3+1]=cy; centers[r*3+2]=cz; }
  }
}

// ---------- fallback FPS (only if ws too small) ----------
__global__ void __launch_bounds__(F2_THR)
fps_safe_kernel(const float* __restrict__ x, unsigned long long* __restrict__ slots,
                unsigned int* __restrict__ cnts, float* __restrict__ centers)
{
  __shared__ unsigned long long red[F2_THR/64];
  const int t = blockIdx.x * F2_THR + threadIdx.x;
  float px[F2_P], py[F2_P], pz[F2_P], d[F2_P];
#pragma unroll
  for (int k = 0; k < F2_P; ++k) {
    int p = t + k * F2_TT;
    px[k] = x[p*3+0]; py[k] = x[p*3+1]; pz[k] = x[p*3+2];
    d[k] = 1e10f;
  }
  float cx = x[0], cy = x[1], cz = x[2];
  if (blockIdx.x == 0 && threadIdx.x == 0) {
    centers[0] = cx; centers[1] = cy; centers[2] = cz;
  }
  for (int r = 1; r < N_GRP; ++r) {
    unsigned long long best = 0ull;
#pragma unroll
    for (int k = 0; k < F2_P; ++k) {
      float e0 = px[k]-cx, e1 = py[k]-cy, e2 = pz[k]-cz;
      float dist = fmaf(e2,e2, fmaf(e1,e1, e0*e0));
      float dn = fminf(d[k], dist);
      d[k] = dn;
      unsigned long long pk = ((unsigned long long)__float_as_uint(dn) << 32)
                            | (0xFFFFFFFFu - (unsigned)(t + k*F2_TT));
      if (pk > best) best = pk;
    }
#pragma unroll
    for (int off = 32; off; off >>= 1) {
      unsigned long long o = __shfl_down(best, off);
      if (o > best) best = o;
    }
    const int wid = threadIdx.x >> 6;
    if ((threadIdx.x & 63) == 0) red[wid] = best;
    __syncthreads();
    if (threadIdx.x == 0) {
#pragma unroll
      for (int w = 1; w < F2_THR/64; ++w) if (red[w] > best) best = red[w];
      atomicMax(&slots[r], best);
      __hip_atomic_fetch_add(&cnts[r], 1u, __ATOMIC_RELEASE, __HIP_MEMORY_SCOPE_AGENT);
      while (__hip_atomic_load(&cnts[r], __ATOMIC_ACQUIRE, __HIP_MEMORY_SCOPE_AGENT) < F2_BLOCKS)
        __builtin_amdgcn_s_sleep(1);
      red[0] = __hip_atomic_load(&slots[r], __ATOMIC_RELAXED, __HIP_MEMORY_SCOPE_AGENT);
    }
    __syncthreads();
    const unsigned long long win = red[0];
    const int widx = (int)(0xFFFFFFFFu - (unsigned int)(win & 0xFFFFFFFFull));
    cx = x[widx*3+0]; cy = x[widx*3+1]; cz = x[widx*3+2];
    if (blockIdx.x == 0 && threadIdx.x == 0) {
      centers[r*3+0] = cx; centers[r*3+1] = cy; centers[r*3+2] = cz;
    }
    __syncthreads();
  }
}

// ---------- Phase 2: per-group exact 32 smallest (proven) ----------
#define TKT 256
#define CAP 3072

__global__ void __launch_bounds__(TKT)
topk_kernel(const float* __restrict__ x, const float* __restrict__ feat,
            const float* __restrict__ centers, float* __restrict__ out)
{
  __shared__ float cv[CAP];
  __shared__ int   ci[CAP];
  __shared__ int   s_cnt;
  __shared__ float s_thr;
  __shared__ float selv[K_NB];
  __shared__ int   seli[K_NB];

  const int g = blockIdx.x, tid = threadIdx.x;
  const float cx = centers[g*3+0], cy = centers[g*3+1], cz = centers[g*3+2];
  const float c2 = fmaf(cz,cz, fmaf(cy,cy, cx*cx));
  if (tid == 0) { s_cnt = 0; s_thr = __builtin_inff(); }
  __syncthreads();

  const int CH = N_PTS / (TKT*8);
  for (int chunk = 0; chunk < CH; ++chunk) {
    const float lthr = s_thr;
#pragma unroll
    for (int k = 0; k < 8; ++k) {
      int p = (chunk*8 + k)*TKT + tid;
      float q0 = x[p*3+0], q1 = x[p*3+1], q2 = x[p*3+2];
      float dot  = fmaf(cz,q2, fmaf(cy,q1, cx*q0));
      float pp   = fmaf(q2,q2, fmaf(q1,q1, q0*q0));
      float dist = fmaf(-2.0f, dot, c2) + pp;
      if (dist <= lthr) {
        int pos = atomicAdd(&s_cnt, 1);
        cv[pos] = dist; ci[pos] = p;
      }
    }
    __syncthreads();
    const int n = s_cnt;
    const bool last = (chunk == CH-1);
    if (n > (CAP - TKT*8) || last) {
      if (tid < 64) {
        for (int it = 0; it < K_NB; ++it) {
          unsigned long long lk = ~0ull;
          for (int j = tid; j < n; j += 64) {
            unsigned long long kk = packMinKey(cv[j], (unsigned)ci[j]);
            if (kk < lk) lk = kk;
          }
#pragma unroll
          for (int off = 32; off; off >>= 1) {
            unsigned long long o = __shfl_xor(lk, off);
            if (o < lk) lk = o;
          }
          const int mi = (int)(unsigned int)(lk & 0xFFFFFFFFull);
          for (int j = tid; j < n; j += 64)
            if (ci[j] == mi) cv[j] = __builtin_inff();
          if (tid == 0) { selv[it] = unpackMinVal(lk); seli[it] = mi; }
        }
      }
      __syncthreads();
      if (!last) {
        if (tid < K_NB) { cv[tid] = selv[tid]; ci[tid] = seli[tid]; }
        if (tid == 0)   { s_cnt = K_NB; s_thr = selv[K_NB-1]; }
        __syncthreads();
      }
    }
  }

  const long base = (long)g * (K_NB*F_DIM);
#pragma unroll
  for (int m = 0; m < (K_NB*F_DIM)/TKT; ++m) {
    int lin = m*TKT + tid;
    int j = lin >> 6, c = lin & 63;
    out[base + lin] = feat[(long)seli[j]*F_DIM + c];
  }
}

// ---------- Phase 3: per-point argmin over 1024 centers (proven) ----------
__global__ void __launch_bounds__(256)
argmin_kernel(const float* __restrict__ x, const float* __restrict__ centers,
              float* __restrict__ outIdx)
{
  __shared__ float scx[N_GRP], scy[N_GRP], scz[N_GRP], sc2[N_GRP];
  for (int i = threadIdx.x; i < N_GRP; i += 256) {
    float a = centers[i*3+0], b = centers[i*3+1], c = centers[i*3+2];
    scx[i]=a; scy[i]=b; scz[i]=c;
    sc2[i] = fmaf(c,c, fmaf(b,b, a*a));
  }
  __syncthreads();
  const int p = blockIdx.x*256 + threadIdx.x;
  const float q0 = x[p*3+0], q1 = x[p*3+1], q2 = x[p*3+2];
  const float pp = fmaf(q2,q2, fmaf(q1,q1, q0*q0));
  float best = __builtin_inff(); int bi = 0;
#pragma unroll 4
  for (int c = 0; c < N_GRP; ++c) {
    float dot  = fmaf(scz[c],q2, fmaf(scy[c],q1, scx[c]*q0));
    float dist = fmaf(-2.0f, dot, sc2[c]) + pp;
    if (dist < best) { best = dist; bi = c; }
  }
  outIdx[p] = (float)bi;
}

// ---------- launch ----------
extern "C" void kernel_launch(void* const* d_in, const int* in_sizes, int n_in,
                              void* d_out, int out_size, void* d_ws, size_t ws_size,
                              hipStream_t stream)
{
  const float* x    = (const float*)d_in[0];
  const float* feat = (const float*)d_in[1];
  float* out = (float*)d_out;
  char* ws = (char*)d_ws;

  float* ctr = (float*)ws;                                   // 12 KiB centers @ 0
  const size_t DD_OFF  = 65536;                              // 256 KiB d array
  const size_t XS_OFF  = DD_OFF + (size_t)N_PTS*4;           // 1 MiB float4 pts
  const size_t NEED    = XS_OFF + (size_t)N_PTS*16;

  if (ws_size >= NEED) {
    float*  dd  = (float*)(ws + DD_OFF);
    float4* xs4 = (float4*)(ws + XS_OFF);
    hipLaunchKernelGGL(fps_kernel, dim3(1), dim3(FPS1_THR), 0, stream, x, xs4, dd, ctr);
  } else {
    unsigned long long* slots = (unsigned long long*)(ws + 16384);
    unsigned int*       cnts  = (unsigned int*)(ws + 24576);
    hipMemsetAsync(ws + 16384, 0, 12288, stream);
    hipLaunchKernelGGL(fps_safe_kernel, dim3(F2_BLOCKS), dim3(F2_THR), 0, stream,
                       x, slots, cnts, ctr);
  }
  hipLaunchKernelGGL(topk_kernel, dim3(N_GRP), dim3(TKT), 0, stream, x, feat, ctr, out);
  hipLaunchKernelGGL(argmin_kernel, dim3(N_PTS/256), dim3(256), 0, stream,
                     x, ctr, out + (size_t)N_GRP*K_NB*F_DIM);
}